// Round 1
// baseline (1747.107 us; speedup 1.0000x reference)
//
#include <hip/hip_runtime.h>
#include <math.h>

#define NPTS 16384
#define KNB  16
#define D    512

// ---------------------------------------------------------------------------
// knn dtype normalize: JAX may hand us int64 (x64 on) or int32 (x64 off).
// If int64 little-endian, words 1,3,5,7 are high halves == 0 (indices <2^31).
// Probability of false positive under int32 (4 random idx in [0,16384) all 0)
// is ~(1/16384)^4 — negligible. Uniform branch, same work every call.
// ---------------------------------------------------------------------------
__global__ void knn_convert_kernel(const int* __restrict__ raw,
                                   int* __restrict__ out) {
  bool is64 = (raw[1] == 0) && (raw[3] == 0) && (raw[5] == 0) && (raw[7] == 0);
  int e = blockIdx.x * 256 + threadIdx.x;   // grid covers NPTS*KNB exactly
  out[e] = is64 ? raw[2 * e] : raw[e];
}

// geo_mean[n] = mean_k (diff_xyz, |diff|)  -> [N,4]
__global__ void geo_kernel(const float* __restrict__ pts,
                           const int* __restrict__ knn,
                           float4* __restrict__ gm) {
  int n = blockIdx.x * 256 + threadIdx.x;
  float px = pts[n * 3 + 0], py = pts[n * 3 + 1], pz = pts[n * 3 + 2];
  float ax = 0.f, ay = 0.f, az = 0.f, an = 0.f;
#pragma unroll
  for (int k = 0; k < KNB; ++k) {
    int idx = knn[n * KNB + k];
    float dx = px - pts[idx * 3 + 0];
    float dy = py - pts[idx * 3 + 1];
    float dz = pz - pts[idx * 3 + 2];
    float nr = sqrtf(dx * dx + dy * dy + dz * dz);
    ax += dx; ay += dy; az += dz; an += nr;
  }
  const float r = 1.f / 16.f;
  gm[n] = make_float4(ax * r, ay * r, az * r, an * r);
}

// sgeo = S * geo_mean  -> [N,4]
__global__ void sgeo_kernel(const int* __restrict__ knn,
                            const float4* __restrict__ gm,
                            float4* __restrict__ sg) {
  int n = blockIdx.x * 256 + threadIdx.x;
  float ax = 0.f, ay = 0.f, az = 0.f, aw = 0.f;
#pragma unroll
  for (int k = 0; k < KNB; ++k) {
    float4 g = gm[knn[n * KNB + k]];
    ax += g.x; ay += g.y; az += g.z; aw += g.w;
  }
  const float r = 1.f / 16.f;
  sg[n] = make_float4(ax * r, ay * r, az * r, aw * r);
}

// P = W2a*Wl2 [512,4], Q = W2b*Wl1 [512,4],
// btot = b_mlp2 + b_res + W2a*b_lfa2 + W2b*b_lfa1 + W2c*b_mlp1  [512]
__global__ void pq_kernel(const float* __restrict__ w_mlp2,
                          const float* __restrict__ w_lfa1,
                          const float* __restrict__ w_lfa2,
                          const float* __restrict__ b_mlp1,
                          const float* __restrict__ b_lfa1,
                          const float* __restrict__ b_lfa2,
                          const float* __restrict__ b_mlp2,
                          const float* __restrict__ b_res,
                          float4* __restrict__ P, float4* __restrict__ Q,
                          float* __restrict__ btot) {
  int j = blockIdx.x * 256 + threadIdx.x;  // < 512
  const float* wrow = w_mlp2 + (size_t)j * D;
  float p0 = 0, p1 = 0, p2 = 0, p3 = 0;
  float bt = b_mlp2[j] + b_res[j];
  for (int i = 0; i < 256; ++i) {
    float w = wrow[i];
    p0 += w * w_lfa2[i * 4 + 0]; p1 += w * w_lfa2[i * 4 + 1];
    p2 += w * w_lfa2[i * 4 + 2]; p3 += w * w_lfa2[i * 4 + 3];
    bt += w * b_lfa2[i];
  }
  float q0 = 0, q1 = 0, q2 = 0, q3 = 0;
  for (int i = 0; i < 128; ++i) {
    float w = wrow[256 + i];
    q0 += w * w_lfa1[i * 4 + 0]; q1 += w * w_lfa1[i * 4 + 1];
    q2 += w * w_lfa1[i * 4 + 2]; q3 += w * w_lfa1[i * 4 + 3];
    bt += w * b_lfa1[i];
  }
  for (int i = 0; i < 128; ++i) bt += wrow[384 + i] * b_mlp1[i];
  P[j] = make_float4(p0, p1, p2, p3);
  Q[j] = make_float4(q0, q1, q2, q3);
  btot[j] = bt;
}

// M[j][k] = sum_i w_mlp2[j][384+i] * w_mlp1[i][k]   (M = W2c * W1, 512x512)
__global__ void m_kernel(const float* __restrict__ w_mlp2,
                         const float* __restrict__ w_mlp1,
                         float* __restrict__ M) {
  int e = blockIdx.x * 256 + threadIdx.x;  // < 512*512
  int j = e >> 9, k = e & 511;
  const float* wrow = w_mlp2 + (size_t)j * D + 384;
  float s = 0.f;
  for (int i = 0; i < 128; ++i) s += wrow[i] * w_mlp1[(size_t)i * D + k];
  M[e] = s;
}

// f1 = Cb  (elementwise from gm/sg/P/Q/btot)
__global__ void cb_kernel(const float4* __restrict__ gm,
                          const float4* __restrict__ sg,
                          const float4* __restrict__ P,
                          const float4* __restrict__ Q,
                          const float* __restrict__ btot,
                          float* __restrict__ out) {
  int e = blockIdx.x * 256 + threadIdx.x;  // < NPTS*D
  int n = e >> 9, j = e & 511;
  float4 g = gm[n], s = sg[n], p = P[j], q = Q[j];
  out[e] = g.x * p.x + g.y * p.y + g.z * p.z + g.w * p.w +
           s.x * q.x + s.y * q.y + s.z * q.z + s.w * q.w + btot[j];
}

// out[n][:] = mean_k in[knn[n,k]][:]   ([N,512] gather-mean)
__global__ __launch_bounds__(256) void gather_kernel(
    const int* __restrict__ knn, const float* __restrict__ in,
    float* __restrict__ out) {
  __shared__ int sidx[KNB];
  int n = blockIdx.x;
  if (threadIdx.x < KNB) sidx[threadIdx.x] = knn[n * KNB + threadIdx.x];
  __syncthreads();
  int c = threadIdx.x * 2;
  float a0 = 0.f, a1 = 0.f;
#pragma unroll
  for (int k = 0; k < KNB; ++k) {
    const float2 v = *(const float2*)(in + (size_t)sidx[k] * D + c);
    a0 += v.x; a1 += v.y;
  }
  const float r = 1.f / 16.f;
  *(float2*)(out + (size_t)n * D + c) = make_float2(a0 * r, a1 * r);
}

// ---------------------------------------------------------------------------
// Dual GEMM + epilogue:
//   out[n][j] = acc( s2[n][:]·M[j][:] + f[n][:]·Wres[j][:] )
//              + Cb(n,j) + f[n][j]
// Tile 128x128, BK=8, 256 threads, 8x8 microtile per thread.
// LDS k-major with +4-word skew at row>=64 => worst 2-way conflicts (free).
// ---------------------------------------------------------------------------
#define GBM 128
#define GBN 128
#define GBK 8
#define LDP 136

__device__ __forceinline__ void stash(float S[GBK][LDP], int kc, int row,
                                      float4 v) {
  int r = row + ((row >= 64) ? 4 : 0);
  S[kc + 0][r] = v.x; S[kc + 1][r] = v.y;
  S[kc + 2][r] = v.z; S[kc + 3][r] = v.w;
}

__global__ __launch_bounds__(256) void gemm_kernel(
    const float* __restrict__ A1,   // s2   [N,512]
    const float* __restrict__ A2,   // f    [N,512]
    const float* __restrict__ W1,   // M    [512,512]
    const float* __restrict__ W2,   // wres [512,512]
    const float4* __restrict__ gm, const float4* __restrict__ sg,
    const float4* __restrict__ P, const float4* __restrict__ Q,
    const float* __restrict__ btot, float* __restrict__ outp) {
  __shared__ __align__(16) float As1[GBK][LDP];
  __shared__ __align__(16) float As2[GBK][LDP];
  __shared__ __align__(16) float Ws1[GBK][LDP];
  __shared__ __align__(16) float Ws2[GBK][LDP];

  const int tid = threadIdx.x;
  const int tx = tid & 15;        // col group (8 cols each)
  const int ty = tid >> 4;        // row group (8 rows each)
  const int rb = blockIdx.y * GBM;
  const int cb = blockIdx.x * GBN;
  const int srow = tid >> 1;           // 0..127 staging row
  const int skc  = (tid & 1) * 4;      // 0 or 4

  const int aoff = ty * 8 + ((ty >= 8) ? 4 : 0);
  const int woff = tx * 8 + ((tx >= 8) ? 4 : 0);

  float acc[8][8] = {};

  for (int kt = 0; kt < D; kt += GBK) {
    int kk = kt + skc;
    float4 a1v = *(const float4*)(A1 + (size_t)(rb + srow) * D + kk);
    float4 a2v = *(const float4*)(A2 + (size_t)(rb + srow) * D + kk);
    float4 w1v = *(const float4*)(W1 + (size_t)(cb + srow) * D + kk);
    float4 w2v = *(const float4*)(W2 + (size_t)(cb + srow) * D + kk);
    __syncthreads();
    stash(As1, skc, srow, a1v);
    stash(As2, skc, srow, a2v);
    stash(Ws1, skc, srow, w1v);
    stash(Ws2, skc, srow, w2v);
    __syncthreads();
#pragma unroll
    for (int k = 0; k < GBK; ++k) {
      float af1[8], af2[8], wf1[8], wf2[8];
      *(float4*)&af1[0] = *(const float4*)&As1[k][aoff];
      *(float4*)&af1[4] = *(const float4*)&As1[k][aoff + 4];
      *(float4*)&af2[0] = *(const float4*)&As2[k][aoff];
      *(float4*)&af2[4] = *(const float4*)&As2[k][aoff + 4];
      *(float4*)&wf1[0] = *(const float4*)&Ws1[k][woff];
      *(float4*)&wf1[4] = *(const float4*)&Ws1[k][woff + 4];
      *(float4*)&wf2[0] = *(const float4*)&Ws2[k][woff];
      *(float4*)&wf2[4] = *(const float4*)&Ws2[k][woff + 4];
#pragma unroll
      for (int i = 0; i < 8; ++i)
#pragma unroll
        for (int j = 0; j < 8; ++j)
          acc[i][j] += af1[i] * wf1[j] + af2[i] * wf2[j];
    }
  }

  // epilogue: + Cb(n,j) + f[n][j]
#pragma unroll
  for (int i = 0; i < 8; ++i) {
    int n = rb + ty * 8 + i;
    float4 g = gm[n], s = sg[n];
    const float* frow = A2 + (size_t)n * D;
    float* orow = outp + (size_t)n * D;
#pragma unroll
    for (int jj = 0; jj < 8; jj += 4) {
      int col0 = cb + tx * 8 + jj;
      float4 fv = *(const float4*)(frow + col0);
      const float* fp = &fv.x;
      float4 r;
      float* rp = &r.x;
#pragma unroll
      for (int c = 0; c < 4; ++c) {
        int col = col0 + c;
        float4 p = P[col], q = Q[col];
        float cbv = g.x * p.x + g.y * p.y + g.z * p.z + g.w * p.w +
                    s.x * q.x + s.y * q.y + s.z * q.z + s.w * q.w + btot[col];
        rp[c] = acc[i][jj + c] + cbv + fp[c];
      }
      *(float4*)(orow + col0) = r;
    }
  }
}

extern "C" void kernel_launch(void* const* d_in, const int* in_sizes, int n_in,
                              void* d_out, int out_size, void* d_ws,
                              size_t ws_size, hipStream_t stream) {
  const float* inputs = (const float*)d_in[0];
  const int* knn_raw  = (const int*)d_in[1];
  const float* w_mlp1 = (const float*)d_in[2];
  const float* b_mlp1 = (const float*)d_in[3];
  const float* w_lfa1 = (const float*)d_in[4];
  const float* b_lfa1 = (const float*)d_in[5];
  const float* w_lfa2 = (const float*)d_in[6];
  const float* b_lfa2 = (const float*)d_in[7];
  const float* w_mlp2 = (const float*)d_in[8];
  const float* b_mlp2 = (const float*)d_in[9];
  const float* w_res  = (const float*)d_in[10];
  const float* b_res  = (const float*)d_in[11];
  float* out = (float*)d_out;

  // workspace layout (floats); total ~25.83M floats ~= 103.3 MB
  float* ws   = (float*)d_ws;
  float* gm   = ws + 0;         // 65536
  float* sg   = ws + 65536;     // 65536
  float* Pb   = ws + 131072;    // 2048
  float* Qb   = ws + 133120;    // 2048
  float* btot = ws + 135168;    // 512 (+pad)
  float* Mw   = ws + 136192;    // 262144
  float* fA   = ws + 398336;    // 8388608
  float* s1   = ws + 8786944;   // 8388608
  float* s2   = ws + 17175552;  // 8388608
  int* knn_i  = (int*)(ws + 25564160);  // 262144 ints

  knn_convert_kernel<<<NPTS * KNB / 256, 256, 0, stream>>>(knn_raw, knn_i);
  geo_kernel<<<NPTS / 256, 256, 0, stream>>>(inputs, knn_i, (float4*)gm);
  sgeo_kernel<<<NPTS / 256, 256, 0, stream>>>(knn_i, (const float4*)gm,
                                              (float4*)sg);
  pq_kernel<<<2, 256, 0, stream>>>(w_mlp2, w_lfa1, w_lfa2, b_mlp1, b_lfa1,
                                   b_lfa2, b_mlp2, b_res, (float4*)Pb,
                                   (float4*)Qb, btot);
  m_kernel<<<512 * 512 / 256, 256, 0, stream>>>(w_mlp2, w_mlp1, Mw);
  // f1 = Cb
  cb_kernel<<<NPTS * D / 256, 256, 0, stream>>>(
      (const float4*)gm, (const float4*)sg, (const float4*)Pb,
      (const float4*)Qb, btot, fA);

  float* fcur = fA;
  float* fnxt = out;
  for (int t = 0; t < 3; ++t) {
    gather_kernel<<<NPTS, 256, 0, stream>>>(knn_i, fcur, s1);
    gather_kernel<<<NPTS, 256, 0, stream>>>(knn_i, s1, s2);
    gemm_kernel<<<dim3(GBN == 128 ? 4 : 512 / GBN, NPTS / GBM), 256, 0,
                  stream>>>(s2, fcur, Mw, w_res, (const float4*)gm,
                            (const float4*)sg, (const float4*)Pb,
                            (const float4*)Qb, btot, fnxt);
    float* tmp = fcur; fcur = fnxt; fnxt = tmp;
  }
  // after 3 iterations the final write landed in d_out
}

// Round 2
// 271.580 us; speedup vs baseline: 6.4331x; 6.4331x over previous
//
#include <hip/hip_runtime.h>
#include <math.h>

#define NPTS 16384
#define KNB  16
#define D    512

// ---------------------------------------------------------------------------
// Closed-form restructure. With S = gather-mean operator, R = Wres^T + I,
// M = W2c*W1 (so the per-block map is f' = Cb + S^2 f M^T + f R), and f0 = 0:
//   f4 = Cb*(I+R+R^2+R^3)
//      + S^2Cb*(M' + RM' + R^2M' + M'R + RM'R + M'RR)   [M' = M^T]
//      + S^4Cb*(M'M' + RM'M' + M'RM' + M'M'R)
//      + S^6Cb*(M'M'M')
// Cb = [gm, S gm, 1] * Z^T with Z = [P|Q|btot] (rank 9), and S commutes with
// right-multiplication, so each term needs only z*(word) with z = Z^T [9,512].
// Final output = [s^0..s^7 gm, 1] ([N,33]) x Ecat ([33,512]).
// ---------------------------------------------------------------------------

// knn dtype normalize (int64 vs int32 detect; see round-0 note).
__global__ void knn_convert_kernel(const int* __restrict__ raw,
                                   int* __restrict__ out) {
  bool is64 = (raw[1] == 0) && (raw[3] == 0) && (raw[5] == 0) && (raw[7] == 0);
  int e = blockIdx.x * 256 + threadIdx.x;   // grid covers NPTS*KNB exactly
  out[e] = is64 ? raw[2 * e] : raw[e];
}

// s0[n] = geo_mean[n] = mean_k (diff_xyz, |diff|)  -> [N,4]
__global__ void geo_kernel(const float* __restrict__ pts,
                           const int* __restrict__ knn,
                           float4* __restrict__ gm) {
  int n = blockIdx.x * 256 + threadIdx.x;
  float px = pts[n * 3 + 0], py = pts[n * 3 + 1], pz = pts[n * 3 + 2];
  float ax = 0.f, ay = 0.f, az = 0.f, an = 0.f;
#pragma unroll
  for (int k = 0; k < KNB; ++k) {
    int idx = knn[n * KNB + k];
    float dx = px - pts[idx * 3 + 0];
    float dy = py - pts[idx * 3 + 1];
    float dz = pz - pts[idx * 3 + 2];
    float nr = sqrtf(dx * dx + dy * dy + dz * dz);
    ax += dx; ay += dy; az += dz; an += nr;
  }
  const float r = 1.f / 16.f;
  gm[n] = make_float4(ax * r, ay * r, az * r, an * r);
}

// out[n] = mean_k in[knn[n,k]]  ([N,4] gather-mean; applied 7x for s1..s7)
__global__ void sgeo_kernel(const int* __restrict__ knn,
                            const float4* __restrict__ in,
                            float4* __restrict__ out) {
  int n = blockIdx.x * 256 + threadIdx.x;
  float ax = 0.f, ay = 0.f, az = 0.f, aw = 0.f;
#pragma unroll
  for (int k = 0; k < KNB; ++k) {
    float4 g = in[knn[n * KNB + k]];
    ax += g.x; ay += g.y; az += g.z; aw += g.w;
  }
  const float r = 1.f / 16.f;
  out[n] = make_float4(ax * r, ay * r, az * r, aw * r);
}

// z rows 0..3 = P^T (W2a*Wl2), 4..7 = Q^T (W2b*Wl1), 8 = btot. fp64 acc.
__global__ void pq_kernel(const float* __restrict__ w_mlp2,
                          const float* __restrict__ w_lfa1,
                          const float* __restrict__ w_lfa2,
                          const float* __restrict__ b_mlp1,
                          const float* __restrict__ b_lfa1,
                          const float* __restrict__ b_lfa2,
                          const float* __restrict__ b_mlp2,
                          const float* __restrict__ b_res,
                          float* __restrict__ z) {
  int j = blockIdx.x * 256 + threadIdx.x;  // < 512
  const float* wrow = w_mlp2 + (size_t)j * D;
  double p0 = 0, p1 = 0, p2 = 0, p3 = 0;
  double bt = (double)b_mlp2[j] + (double)b_res[j];
  for (int i = 0; i < 256; ++i) {
    double w = wrow[i];
    p0 += w * w_lfa2[i * 4 + 0]; p1 += w * w_lfa2[i * 4 + 1];
    p2 += w * w_lfa2[i * 4 + 2]; p3 += w * w_lfa2[i * 4 + 3];
    bt += w * b_lfa2[i];
  }
  double q0 = 0, q1 = 0, q2 = 0, q3 = 0;
  for (int i = 0; i < 128; ++i) {
    double w = wrow[256 + i];
    q0 += w * w_lfa1[i * 4 + 0]; q1 += w * w_lfa1[i * 4 + 1];
    q2 += w * w_lfa1[i * 4 + 2]; q3 += w * w_lfa1[i * 4 + 3];
    bt += w * b_lfa1[i];
  }
  for (int i = 0; i < 128; ++i) bt += (double)wrow[384 + i] * b_mlp1[i];
  z[0 * D + j] = (float)p0; z[1 * D + j] = (float)p1;
  z[2 * D + j] = (float)p2; z[3 * D + j] = (float)p3;
  z[4 * D + j] = (float)q0; z[5 * D + j] = (float)q1;
  z[6 * D + j] = (float)q2; z[7 * D + j] = (float)q3;
  z[8 * D + j] = (float)bt;
}

// Mt[a][b] = M[b][a] = sum_{i<128} w_mlp2[b][384+i]*w_mlp1[i][a]  (M^T)
__global__ void mt_kernel(const float* __restrict__ w_mlp2,
                          const float* __restrict__ w_mlp1,
                          float* __restrict__ Mt) {
  int e = blockIdx.x * 256 + threadIdx.x;  // < 512*512
  int a = e >> 9, b = e & 511;
  double s = 0.0;
  for (int i = 0; i < 128; ++i)
    s += (double)w_mlp2[(size_t)b * D + 384 + i] * (double)w_mlp1[(size_t)i * D + a];
  Mt[e] = (float)s;
}

// Rm[i][j] = w_res[j][i] + (i==j)
__global__ void rt_kernel(const float* __restrict__ w_res,
                          float* __restrict__ Rm) {
  int e = blockIdx.x * 256 + threadIdx.x;
  int i = e >> 9, j = e & 511;
  Rm[e] = w_res[(size_t)j * D + i] + ((i == j) ? 1.0f : 0.0f);
}

// weight-space word chains: dst = src * (mat ? Rm : M^T), [9,512]x[512,512]
struct Job { int src, mat, dst; };
__device__ __constant__ Job g_jobs[14] = {
  {0,1,1},{0,0,4},                                           // depth 1
  {1,1,2},{1,0,5},{4,1,6},{4,0,7},                           // depth 2
  {2,1,3},{2,0,8},{5,1,9},{5,0,11},{6,1,10},{6,0,12},{7,1,13},{7,0,14} // depth 3
};
// slots: 0 z | 1 zR | 2 zR2 | 3 zR3 | 4 zM | 5 zRM | 6 zMR | 7 zMM |
//        8 zR2M | 9 zRMR | 10 zMRR | 11 zRMM | 12 zMRM | 13 zMMR | 14 zMMM
#define ZSTR 4608  // 9*512

__global__ __launch_bounds__(512) void chain_kernel(float* __restrict__ zbuf,
                                                    const float* __restrict__ Rm,
                                                    const float* __restrict__ Mt,
                                                    int jbase) {
  Job jb = g_jobs[jbase + blockIdx.x / 9];
  int c = blockIdx.x % 9;
  const float* src = zbuf + jb.src * ZSTR + c * D;
  const float* B = jb.mat ? Rm : Mt;
  int j = threadIdx.x;
  double acc = 0.0;
  for (int i = 0; i < D; ++i)
    acc += (double)src[i] * (double)B[(size_t)i * D + j];
  zbuf[jb.dst * ZSTR + c * D + j] = (float)acc;
}

// Ecat [33,512]: rows 0..7 E1(z-rows 0..7), 8..15 E2, 16..23 E3, 24..31 E4,
// row 32 = sum of ALL 15 slots at z-row 8 (bias).
__device__ __constant__ int g_eslots[4][6] = {
  {0, 1, 2, 3, -1, -1},
  {4, 5, 8, 6, 9, 10},
  {7, 11, 12, 13, -1, -1},
  {14, -1, -1, -1, -1, -1}};

__global__ __launch_bounds__(512) void combine_kernel(
    const float* __restrict__ zbuf, float* __restrict__ Ecat) {
  int r = blockIdx.x;  // < 33
  int j = threadIdx.x;
  float s = 0.f;
  if (r < 32) {
    int ci = r >> 3, c = r & 7;
#pragma unroll
    for (int u = 0; u < 6; ++u) {
      int sl = g_eslots[ci][u];
      if (sl >= 0) s += zbuf[sl * ZSTR + c * D + j];
    }
  } else {
#pragma unroll
    for (int sl = 0; sl < 15; ++sl) s += zbuf[sl * ZSTR + 8 * D + j];
  }
  Ecat[r * D + j] = s;
}

// out[n][j] = sum_{r<32} coef[n][r]*Ecat[r][j] + Ecat[32][j]
// coef[n][4k+c] = component c of s_k[n]. Tile 64 pts x 64 cols, 256 thr, 4x4.
__global__ __launch_bounds__(256) void out_kernel(
    const float4* __restrict__ sb,   // s_k[n] = sb[k*16384+n], k<8
    const float* __restrict__ Ecat,
    float* __restrict__ outp) {
  __shared__ float As[33][72];
  __shared__ float Bs[33][72];
  const int n0 = blockIdx.y * 64, c0 = blockIdx.x * 64;
  const int t = threadIdx.x;
  for (int e = t; e < 512; e += 256) {
    int k = e >> 6, p = e & 63;
    float4 v = sb[k * NPTS + n0 + p];
    As[4 * k + 0][p] = v.x; As[4 * k + 1][p] = v.y;
    As[4 * k + 2][p] = v.z; As[4 * k + 3][p] = v.w;
  }
  if (t < 64) As[32][t] = 1.0f;
  for (int e = t; e < 33 * 64; e += 256) {
    int r = e >> 6, c = e & 63;
    Bs[r][c] = Ecat[r * D + c0 + c];
  }
  __syncthreads();
  const int tx = t & 15, ty = t >> 4;
  float acc[4][4] = {};
#pragma unroll
  for (int k = 0; k < 33; ++k) {
    float4 a = *(const float4*)&As[k][ty * 4];
    float4 b = *(const float4*)&Bs[k][tx * 4];
    const float* ap = &a.x; const float* bp = &b.x;
#pragma unroll
    for (int i = 0; i < 4; ++i)
#pragma unroll
      for (int j = 0; j < 4; ++j) acc[i][j] += ap[i] * bp[j];
  }
#pragma unroll
  for (int i = 0; i < 4; ++i) {
    float4 r; r.x = acc[i][0]; r.y = acc[i][1]; r.z = acc[i][2]; r.w = acc[i][3];
    *(float4*)&outp[(size_t)(n0 + ty * 4 + i) * D + c0 + tx * 4] = r;
  }
}

extern "C" void kernel_launch(void* const* d_in, const int* in_sizes, int n_in,
                              void* d_out, int out_size, void* d_ws,
                              size_t ws_size, hipStream_t stream) {
  const float* inputs = (const float*)d_in[0];
  const int* knn_raw  = (const int*)d_in[1];
  const float* w_mlp1 = (const float*)d_in[2];
  const float* b_mlp1 = (const float*)d_in[3];
  const float* w_lfa1 = (const float*)d_in[4];
  const float* b_lfa1 = (const float*)d_in[5];
  const float* w_lfa2 = (const float*)d_in[6];
  const float* b_lfa2 = (const float*)d_in[7];
  const float* w_mlp2 = (const float*)d_in[8];
  const float* b_mlp2 = (const float*)d_in[9];
  const float* w_res  = (const float*)d_in[10];
  const float* b_res  = (const float*)d_in[11];
  float* out = (float*)d_out;

  // workspace layout (floats): ~5.6 MB total
  float* ws    = (float*)d_ws;
  float* sbase = ws + 0;            // 8 * 65536 = 524288   (s0..s7, [N,4])
  float* zbuf  = ws + 524288;       // 15 * 4608 = 69120
  float* Ecat  = ws + 593408;       // 33 * 512  = 16896
  float* Mt    = ws + 610304;       // 262144
  float* Rm    = ws + 872448;       // 262144
  int*   knn_i = (int*)(ws + 1134592);  // 262144 ints

  knn_convert_kernel<<<NPTS * KNB / 256, 256, 0, stream>>>(knn_raw, knn_i);
  geo_kernel<<<NPTS / 256, 256, 0, stream>>>(inputs, knn_i, (float4*)sbase);
  for (int k = 1; k < 8; ++k) {
    sgeo_kernel<<<NPTS / 256, 256, 0, stream>>>(
        knn_i, (const float4*)(sbase) + (size_t)(k - 1) * NPTS,
        (float4*)(sbase) + (size_t)k * NPTS);
  }
  pq_kernel<<<2, 256, 0, stream>>>(w_mlp2, w_lfa1, w_lfa2, b_mlp1, b_lfa1,
                                   b_lfa2, b_mlp2, b_res, zbuf);
  mt_kernel<<<D * D / 256, 256, 0, stream>>>(w_mlp2, w_mlp1, Mt);
  rt_kernel<<<D * D / 256, 256, 0, stream>>>(w_res, Rm);

  chain_kernel<<<2 * 9, 512, 0, stream>>>(zbuf, Rm, Mt, 0);   // depth 1
  chain_kernel<<<4 * 9, 512, 0, stream>>>(zbuf, Rm, Mt, 2);   // depth 2
  chain_kernel<<<8 * 9, 512, 0, stream>>>(zbuf, Rm, Mt, 6);   // depth 3
  combine_kernel<<<33, 512, 0, stream>>>(zbuf, Ecat);

  out_kernel<<<dim3(D / 64, NPTS / 64), 256, 0, stream>>>(
      (const float4*)sbase, Ecat, out);
}

// Round 3
// 224.545 us; speedup vs baseline: 7.7806x; 1.2095x over previous
//
#include <hip/hip_runtime.h>
#include <math.h>

#define NPTS 16384
#define KNB  16
#define D    512

// ---------------------------------------------------------------------------
// Closed-form restructure (verified round 1-2, absmax 0.0625). With
// S = gather-mean, R = Wres^T + I, M = W2c*W1, f' = Cb + S^2 f M^T + f R,
// f0 = 0:
//   f4 = Cb*(I+R+R^2+R^3)
//      + S^2Cb*(M' + RM' + R^2M' + M'R + RM'R + M'RR)    [M' = M^T]
//      + S^4Cb*(M'M' + RM'M' + M'RM' + M'M'R)
//      + S^6Cb*(M'M'M')
// Cb = [gm, S gm, 1] * Z^T, Z = [P|Q|btot] (rank 9); S commutes with
// right-multiplication -> everything collapses to weight-space words z*word
// (z = Z^T [9,512]) and a final [N,33] x [33,512] product.
// ---------------------------------------------------------------------------

// knn dtype probe: int64 little-endian => odd words are high halves == 0.
// False-positive under int32 needs 4 random idx in [0,16384) all zero:
// (1/16384)^4. Uniform branch.
__device__ __forceinline__ bool knn_is64(const int* __restrict__ raw) {
  return (raw[1] == 0) && (raw[3] == 0) && (raw[5] == 0) && (raw[7] == 0);
}

// s0[n] = geo_mean[n] = mean_k (diff_xyz, |diff|)  -> [N,4]
__global__ void geo_kernel(const float* __restrict__ pts,
                           const int* __restrict__ raw,
                           float4* __restrict__ gm) {
  bool is64 = knn_is64(raw);
  int n = blockIdx.x * 256 + threadIdx.x;
  float px = pts[n * 3 + 0], py = pts[n * 3 + 1], pz = pts[n * 3 + 2];
  float ax = 0.f, ay = 0.f, az = 0.f, an = 0.f;
#pragma unroll
  for (int k = 0; k < KNB; ++k) {
    int e = n * KNB + k;
    int idx = is64 ? raw[2 * e] : raw[e];
    float dx = px - pts[idx * 3 + 0];
    float dy = py - pts[idx * 3 + 1];
    float dz = pz - pts[idx * 3 + 2];
    float nr = sqrtf(dx * dx + dy * dy + dz * dz);
    ax += dx; ay += dy; az += dz; an += nr;
  }
  const float r = 1.f / 16.f;
  gm[n] = make_float4(ax * r, ay * r, az * r, an * r);
}

// out[n] = mean_k in[knn[n,k]]  ([N,4] gather-mean; applied 7x for s1..s7)
__global__ void sgeo_kernel(const int* __restrict__ raw,
                            const float4* __restrict__ in,
                            float4* __restrict__ out) {
  bool is64 = knn_is64(raw);
  int n = blockIdx.x * 256 + threadIdx.x;
  float ax = 0.f, ay = 0.f, az = 0.f, aw = 0.f;
#pragma unroll
  for (int k = 0; k < KNB; ++k) {
    int e = n * KNB + k;
    int idx = is64 ? raw[2 * e] : raw[e];
    float4 g = in[idx];
    ax += g.x; ay += g.y; az += g.z; aw += g.w;
  }
  const float r = 1.f / 16.f;
  out[n] = make_float4(ax * r, ay * r, az * r, aw * r);
}

// z rows 0..3 = P^T (W2a*Wl2), 4..7 = Q^T (W2b*Wl1), 8 = btot. fp64 acc.
// One block per output column j; 256 threads cover the 512 k-elements.
__global__ __launch_bounds__(256) void pq_kernel(
    const float* __restrict__ w_mlp2, const float* __restrict__ w_lfa1,
    const float* __restrict__ w_lfa2, const float* __restrict__ b_mlp1,
    const float* __restrict__ b_lfa1, const float* __restrict__ b_lfa2,
    const float* __restrict__ b_mlp2, const float* __restrict__ b_res,
    float* __restrict__ z) {
  const int j = blockIdx.x;   // < 512
  const int t = threadIdx.x;  // < 256
  const float* wrow = w_mlp2 + (size_t)j * D;
  double acc[9];
#pragma unroll
  for (int u = 0; u < 9; ++u) acc[u] = 0.0;
  {  // i = t in [0,256): W2a segment
    double w = wrow[t];
    acc[0] += w * w_lfa2[t * 4 + 0]; acc[1] += w * w_lfa2[t * 4 + 1];
    acc[2] += w * w_lfa2[t * 4 + 2]; acc[3] += w * w_lfa2[t * 4 + 3];
    acc[8] += w * b_lfa2[t];
  }
  {  // i = t+256: W2b (t<128) or W2c (t>=128) segment
    double w = wrow[t + 256];
    if (t < 128) {
      acc[4] += w * w_lfa1[t * 4 + 0]; acc[5] += w * w_lfa1[t * 4 + 1];
      acc[6] += w * w_lfa1[t * 4 + 2]; acc[7] += w * w_lfa1[t * 4 + 3];
      acc[8] += w * b_lfa1[t];
    } else {
      acc[8] += w * b_mlp1[t - 128];
    }
  }
  __shared__ double red[9][4];
#pragma unroll
  for (int u = 0; u < 9; ++u) {
    double v = acc[u];
#pragma unroll
    for (int o = 32; o > 0; o >>= 1) v += __shfl_down(v, o, 64);
    if ((t & 63) == 0) red[u][t >> 6] = v;
  }
  __syncthreads();
  if (t < 9) {
    double s = red[t][0] + red[t][1] + red[t][2] + red[t][3];
    if (t == 8) s += (double)b_mlp2[j] + (double)b_res[j];
    z[t * D + j] = (float)s;
  }
}

// Mt[a][b] = sum_{i<128} w_mlp2[b][384+i]*w_mlp1[i][a]   (M^T, coalesced in a)
// Rm[i][j] = w_res[j][i] + (i==j)
__global__ void prep_kernel(const float* __restrict__ w_mlp2,
                            const float* __restrict__ w_mlp1,
                            const float* __restrict__ w_res,
                            float* __restrict__ Mt, float* __restrict__ Rm) {
  int e = blockIdx.x * 256 + threadIdx.x;
  if (e < D * D) {
    int a = e & 511, b = e >> 9;  // lanes: consecutive a -> coalesced w_mlp1
    const float* wrow = w_mlp2 + (size_t)b * D + 384;  // wave-broadcast
    double s = 0.0;
#pragma unroll 4
    for (int i = 0; i < 128; ++i)
      s += (double)wrow[i] * (double)w_mlp1[(size_t)i * D + a];
    Mt[(size_t)a * D + b] = (float)s;
  } else {
    int e2 = e - D * D;
    int i = e2 >> 9, j = e2 & 511;
    Rm[e2] = w_res[(size_t)j * D + i] + ((i == j) ? 1.0f : 0.0f);
  }
}

// weight-space word chains: dst = src * (mat ? Rm : M^T), [9,512]x[512,512]
struct Job { int src, mat, dst; };
__device__ __constant__ Job g_jobs[14] = {
  {0,1,1},{0,0,4},                                           // depth 1
  {1,1,2},{1,0,5},{4,1,6},{4,0,7},                           // depth 2
  {2,1,3},{2,0,8},{5,1,9},{5,0,11},{6,1,10},{6,0,12},{7,1,13},{7,0,14} // depth 3
};
// slots: 0 z | 1 zR | 2 zR2 | 3 zR3 | 4 zM | 5 zRM | 6 zMR | 7 zMM |
//        8 zR2M | 9 zRMR | 10 zMRR | 11 zRMM | 12 zMRM | 13 zMMR | 14 zMMM
#define ZSTR 4608  // 9*512

__global__ __launch_bounds__(512) void chain_kernel(float* __restrict__ zbuf,
                                                    const float* __restrict__ Rm,
                                                    const float* __restrict__ Mt,
                                                    int jbase) {
  Job jb = g_jobs[jbase + blockIdx.x / 9];
  int c = blockIdx.x % 9;
  const float* src = zbuf + jb.src * ZSTR + c * D;  // wave-broadcast reads
  const float* B = jb.mat ? Rm : Mt;                // coalesced reads
  int j = threadIdx.x;
  double a0 = 0, a1 = 0, a2 = 0, a3 = 0;
  for (int i = 0; i < D; i += 4) {
    a0 += (double)src[i + 0] * (double)B[(size_t)(i + 0) * D + j];
    a1 += (double)src[i + 1] * (double)B[(size_t)(i + 1) * D + j];
    a2 += (double)src[i + 2] * (double)B[(size_t)(i + 2) * D + j];
    a3 += (double)src[i + 3] * (double)B[(size_t)(i + 3) * D + j];
  }
  zbuf[jb.dst * ZSTR + c * D + j] = (float)((a0 + a1) + (a2 + a3));
}

// Ecat [33,512]: rows 0..7 E1, 8..15 E2, 16..23 E3, 24..31 E4,
// row 32 = sum of ALL 15 slots at z-row 8 (bias).
__device__ __constant__ int g_eslots[4][6] = {
  {0, 1, 2, 3, -1, -1},
  {4, 5, 8, 6, 9, 10},
  {7, 11, 12, 13, -1, -1},
  {14, -1, -1, -1, -1, -1}};

__global__ __launch_bounds__(512) void combine_kernel(
    const float* __restrict__ zbuf, float* __restrict__ Ecat) {
  int r = blockIdx.x;  // < 33
  int j = threadIdx.x;
  float s = 0.f;
  if (r < 32) {
    int ci = r >> 3, c = r & 7;
#pragma unroll
    for (int u = 0; u < 6; ++u) {
      int sl = g_eslots[ci][u];
      if (sl >= 0) s += zbuf[sl * ZSTR + c * D + j];
    }
  } else {
#pragma unroll
    for (int sl = 0; sl < 15; ++sl) s += zbuf[sl * ZSTR + 8 * D + j];
  }
  Ecat[r * D + j] = s;
}

// out[n][j] = sum_{r<32} coef[n][r]*Ecat[r][j] + Ecat[32][j]
// coef[n][4k+c] = component c of s_k[n]. Tile 64 pts x 64 cols, 256 thr, 4x4.
__global__ __launch_bounds__(256) void out_kernel(
    const float4* __restrict__ sb,   // s_k[n] = sb[k*16384+n], k<8
    const float* __restrict__ Ecat,
    float* __restrict__ outp) {
  __shared__ float As[33][72];
  __shared__ float Bs[33][72];
  const int n0 = blockIdx.y * 64, c0 = blockIdx.x * 64;
  const int t = threadIdx.x;
  for (int e = t; e < 512; e += 256) {
    int k = e >> 6, p = e & 63;
    float4 v = sb[k * NPTS + n0 + p];
    As[4 * k + 0][p] = v.x; As[4 * k + 1][p] = v.y;
    As[4 * k + 2][p] = v.z; As[4 * k + 3][p] = v.w;
  }
  if (t < 64) As[32][t] = 1.0f;
  for (int e = t; e < 33 * 64; e += 256) {
    int r = e >> 6, c = e & 63;
    Bs[r][c] = Ecat[r * D + c0 + c];
  }
  __syncthreads();
  const int tx = t & 15, ty = t >> 4;
  float acc[4][4] = {};
#pragma unroll
  for (int k = 0; k < 33; ++k) {
    float4 a = *(const float4*)&As[k][ty * 4];
    float4 b = *(const float4*)&Bs[k][tx * 4];
    const float* ap = &a.x; const float* bp = &b.x;
#pragma unroll
    for (int i = 0; i < 4; ++i)
#pragma unroll
      for (int j = 0; j < 4; ++j) acc[i][j] += ap[i] * bp[j];
  }
#pragma unroll
  for (int i = 0; i < 4; ++i) {
    float4 r; r.x = acc[i][0]; r.y = acc[i][1]; r.z = acc[i][2]; r.w = acc[i][3];
    *(float4*)&outp[(size_t)(n0 + ty * 4 + i) * D + c0 + tx * 4] = r;
  }
}

extern "C" void kernel_launch(void* const* d_in, const int* in_sizes, int n_in,
                              void* d_out, int out_size, void* d_ws,
                              size_t ws_size, hipStream_t stream) {
  const float* inputs = (const float*)d_in[0];
  const int* knn_raw  = (const int*)d_in[1];
  const float* w_mlp1 = (const float*)d_in[2];
  const float* b_mlp1 = (const float*)d_in[3];
  const float* w_lfa1 = (const float*)d_in[4];
  const float* b_lfa1 = (const float*)d_in[5];
  const float* w_lfa2 = (const float*)d_in[6];
  const float* b_lfa2 = (const float*)d_in[7];
  const float* w_mlp2 = (const float*)d_in[8];
  const float* b_mlp2 = (const float*)d_in[9];
  const float* w_res  = (const float*)d_in[10];
  const float* b_res  = (const float*)d_in[11];
  float* out = (float*)d_out;

  // workspace layout (floats): ~4.6 MB total
  float* ws    = (float*)d_ws;
  float* sbase = ws + 0;            // 8 * 65536 = 524288   (s0..s7, [N,4])
  float* zbuf  = ws + 524288;       // 15 * 4608 = 69120
  float* Ecat  = ws + 593408;       // 33 * 512  = 16896
  float* Mt    = ws + 610304;       // 262144
  float* Rm    = ws + 872448;       // 262144

  geo_kernel<<<NPTS / 256, 256, 0, stream>>>(inputs, knn_raw,
                                             (float4*)sbase);
  for (int k = 1; k < 8; ++k) {
    sgeo_kernel<<<NPTS / 256, 256, 0, stream>>>(
        knn_raw, (const float4*)(sbase) + (size_t)(k - 1) * NPTS,
        (float4*)(sbase) + (size_t)k * NPTS);
  }
  pq_kernel<<<D, 256, 0, stream>>>(w_mlp2, w_lfa1, w_lfa2, b_mlp1, b_lfa1,
                                   b_lfa2, b_mlp2, b_res, zbuf);
  prep_kernel<<<2 * D * D / 256, 256, 0, stream>>>(w_mlp2, w_mlp1, w_res,
                                                   Mt, Rm);
  chain_kernel<<<2 * 9, 512, 0, stream>>>(zbuf, Rm, Mt, 0);   // depth 1
  chain_kernel<<<4 * 9, 512, 0, stream>>>(zbuf, Rm, Mt, 2);   // depth 2
  chain_kernel<<<8 * 9, 512, 0, stream>>>(zbuf, Rm, Mt, 6);   // depth 3
  combine_kernel<<<33, 512, 0, stream>>>(zbuf, Ecat);

  out_kernel<<<dim3(D / 64, NPTS / 64), 256, 0, stream>>>(
      (const float4*)sbase, Ecat, out);
}